// Round 4
// baseline (224.946 us; speedup 1.0000x reference)
//
#include <hip/hip_runtime.h>
#include <hip/hip_bf16.h>

// Problem constants (reference: N=2048, F=128, HEADS=8, OUT_DIM=8, ALPHA=0.2)
#define NN      2048
#define FDIM    128
#define HEADS   8
#define ODIM    8
#define HID     64      // HEADS*ODIM
#define ALPHA   0.2f
#define NWORDS  (NN / 64)   // 32 u64 mask words per row

typedef float vfloat4 __attribute__((ext_vector_type(4)));  // clang-native for nontemporal builtins

__device__ __forceinline__ float lrelu(float x) {
    return x > 0.f ? x : ALPHA * x;
}

// ---------------------------------------------------------------------------
// Kernel 1: h = X @ W  (per-node row), s1 = h . a1, s2 = h . a2  (per head)
// grid = NN blocks, block = 64 threads (1 wave)
// ---------------------------------------------------------------------------
__global__ __launch_bounds__(64) void gat_prep(
        const float* __restrict__ X,   // (NN, FDIM)
        const float* __restrict__ W,   // (FDIM, HID)
        const float* __restrict__ ak,  // (2*ODIM,)
        float* __restrict__ H,         // (NN, HID)
        float* __restrict__ S1,        // (NN, HEADS)
        float* __restrict__ S2) {      // (NN, HEADS)
    const int n = blockIdx.x;
    const int t = threadIdx.x;

    __shared__ float Xs[FDIM];
    __shared__ float hs[HID];

    Xs[t]      = X[(size_t)n * FDIM + t];
    Xs[t + 64] = X[(size_t)n * FDIM + 64 + t];
    __syncthreads();

    float acc = 0.f;
    #pragma unroll 8
    for (int k = 0; k < FDIM; ++k)
        acc = fmaf(Xs[k], W[k * HID + t], acc);   // Xs[k]: LDS broadcast; W col: coalesced

    H[(size_t)n * HID + t] = acc;
    hs[t] = acc;
    __syncthreads();

    if (t < 16) {
        const int head = t & 7;
        const float* a = ak + ((t < 8) ? 0 : ODIM);
        float s = 0.f;
        #pragma unroll
        for (int d = 0; d < ODIM; ++d)
            s = fmaf(hs[head * ODIM + d], a[d], s);
        if (t < 8) S1[n * HEADS + head] = s;
        else       S2[n * HEADS + head] = s;
    }
}

// ---------------------------------------------------------------------------
// Kernel 2: per row i — LF[i,h] = sum_j mask(i,j) * exp(lrelu(s1[i,h]+s2[j,h]))
// Max-free softmax denominator (scores O(1); masked lanes contribute exact 0,
// matching reference exp(-1e9 - m) == 0 in fp32). Also packs the adjacency
// row into a 64-bit-per-64-j ballot bitmask for the write kernel.
// grid = NN blocks, block = 512 (8 waves), 4 j per thread. No LDS staging of A.
// ---------------------------------------------------------------------------
__global__ __launch_bounds__(512) void gat_rowsum(
        const int*   __restrict__ A,    // (NN, NN)
        const float* __restrict__ S1,   // (NN, HEADS)
        const float* __restrict__ S2,   // (NN, HEADS)
        float* __restrict__ LF,         // (NN, HEADS)
        unsigned long long* __restrict__ Mb) {  // (NN, NWORDS)
    const int i    = blockIdx.x;
    const int t    = threadIdx.x;
    const int wave = t >> 6;
    const int lane = t & 63;

    __shared__ float redL[8 * HEADS];

    float s1r[HEADS];
    #pragma unroll
    for (int h = 0; h < HEADS; ++h) s1r[h] = S1[i * HEADS + h];

    float ls[HEADS];
    #pragma unroll
    for (int h = 0; h < HEADS; ++h) ls[h] = 0.f;

    #pragma unroll
    for (int jj = 0; jj < 4; ++jj) {
        const int j = t + jj * 512;
        const bool msk = A[(size_t)i * NN + j] > 0;   // coalesced dword

        // pack mask bits: word index j>>6 = wave + jj*8 (wave-uniform)
        const unsigned long long b = __ballot(msk);
        if (lane == 0) Mb[i * NWORDS + wave + jj * 8] = b;

        const float4 s2a = *(const float4*)(S2 + j * HEADS);
        const float4 s2b = *(const float4*)(S2 + j * HEADS + 4);
        const float s2v[8] = {s2a.x, s2a.y, s2a.z, s2a.w,
                              s2b.x, s2b.y, s2b.z, s2b.w};
        #pragma unroll
        for (int h = 0; h < HEADS; ++h) {
            const float x = s1r[h] + s2v[h];
            ls[h] += msk ? __expf(lrelu(x)) : 0.f;
        }
    }

    #pragma unroll
    for (int h = 0; h < HEADS; ++h) {
        float v = ls[h];
        #pragma unroll
        for (int off = 32; off; off >>= 1)
            v += __shfl_xor(v, off);
        if (lane == 0) redL[wave * HEADS + h] = v;
    }
    __syncthreads();

    if (t < HEADS) {
        float v = 0.f;
        #pragma unroll
        for (int w = 0; w < 8; ++w)
            v += redL[w * HEADS + t];
        LF[i * HEADS + t] = v;
    }
}

// ---------------------------------------------------------------------------
// Kernel 3: pure write stream, ZERO barriers, ~300-cycle prologue.
// Per row i: out[i,j,d] = lrelu( sum_h exp(e[i,j,h]) * h[i,h,d] / LF[i,h] ).
// Mask from bitmask (one broadcast 8B load per wave per jj). hh in registers
// via same-address broadcast loads. Nontemporal coalesced float4 stores.
// grid = NN blocks, block = 256 (4 waves), 8 j per thread
// ---------------------------------------------------------------------------
__global__ __launch_bounds__(256, 4) void gat_write(
        const unsigned long long* __restrict__ Mb,  // (NN, NWORDS)
        const float* __restrict__ H,    // (NN, HID)
        const float* __restrict__ S1,   // (NN, HEADS)
        const float* __restrict__ S2,   // (NN, HEADS)
        const float* __restrict__ LF,   // (NN, HEADS)
        float* __restrict__ out) {      // (NN, NN, ODIM)
    const int i    = blockIdx.x;
    const int t    = threadIdx.x;
    const int wave = t >> 6;
    const int lane = t & 63;

    // --- prologue: all broadcast loads (same address across lanes, L1-hit) ---
    float lfr[HEADS];
    {
        const float4 l0 = *(const float4*)(LF + i * HEADS);
        const float4 l1 = *(const float4*)(LF + i * HEADS + 4);
        lfr[0] = 1.f / l0.x; lfr[1] = 1.f / l0.y;
        lfr[2] = 1.f / l0.z; lfr[3] = 1.f / l0.w;
        lfr[4] = 1.f / l1.x; lfr[5] = 1.f / l1.y;
        lfr[6] = 1.f / l1.z; lfr[7] = 1.f / l1.w;
    }
    float hh[HID];
    #pragma unroll
    for (int k = 0; k < HID; k += 4) {
        const float4 v = *(const float4*)(H + (size_t)i * HID + k);
        const float r = lfr[k >> 3];
        hh[k]     = v.x * r; hh[k + 1] = v.y * r;
        hh[k + 2] = v.z * r; hh[k + 3] = v.w * r;
    }
    float s1r[HEADS];
    #pragma unroll
    for (int h = 0; h < HEADS; ++h) s1r[h] = S1[i * HEADS + h];

    #pragma unroll
    for (int jj = 0; jj < 8; ++jj) {
        const int j = t + jj * 256;
        // word index j>>6 = wave + jj*4: wave-uniform broadcast load
        const unsigned long long m = Mb[i * NWORDS + wave + jj * 4];
        const bool msk = (m >> lane) & 1ull;

        const float4 s2a = *(const float4*)(S2 + j * HEADS);
        const float4 s2b = *(const float4*)(S2 + j * HEADS + 4);
        const float s2v[8] = {s2a.x, s2a.y, s2a.z, s2a.w,
                              s2b.x, s2b.y, s2b.z, s2b.w};

        float p[HEADS];
        #pragma unroll
        for (int h = 0; h < HEADS; ++h) {
            const float x = s1r[h] + s2v[h];
            p[h] = msk ? __expf(lrelu(x)) : 0.f;
        }

        float o[ODIM];
        #pragma unroll
        for (int d = 0; d < ODIM; ++d) o[d] = 0.f;
        #pragma unroll
        for (int h = 0; h < HEADS; ++h) {
            #pragma unroll
            for (int d = 0; d < ODIM; ++d)
                o[d] = fmaf(p[h], hh[h * ODIM + d], o[d]);
        }

        const size_t base = ((size_t)i * NN + j) * ODIM;
        vfloat4 o0, o1;
        o0.x = lrelu(o[0]); o0.y = lrelu(o[1]);
        o0.z = lrelu(o[2]); o0.w = lrelu(o[3]);
        o1.x = lrelu(o[4]); o1.y = lrelu(o[5]);
        o1.z = lrelu(o[6]); o1.w = lrelu(o[7]);
        __builtin_nontemporal_store(o0, (vfloat4*)(out + base));
        __builtin_nontemporal_store(o1, (vfloat4*)(out + base + 4));
    }
}

// ---------------------------------------------------------------------------
extern "C" void kernel_launch(void* const* d_in, const int* in_sizes, int n_in,
                              void* d_out, int out_size, void* d_ws, size_t ws_size,
                              hipStream_t stream) {
    const float* X  = (const float*)d_in[0];   // (2048,128) fp32
    const int*   A  = (const int*)  d_in[1];   // (2048,2048) int32
    const float* W  = (const float*)d_in[2];   // (128,64) fp32
    const float* ak = (const float*)d_in[3];   // (16,1) fp32
    float* out = (float*)d_out;                // (2048*2048*8) fp32

    // ws layout: H (512 KB) | S1 (64 KB) | S2 (64 KB) | LF (64 KB) | Mb (512 KB)
    float* H  = (float*)d_ws;
    float* S1 = H  + (size_t)NN * HID;
    float* S2 = S1 + (size_t)NN * HEADS;
    float* LF = S2 + (size_t)NN * HEADS;
    unsigned long long* Mb = (unsigned long long*)(LF + (size_t)NN * HEADS);

    gat_prep  <<<NN,  64, 0, stream>>>(X, W, ak, H, S1, S2);
    gat_rowsum<<<NN, 512, 0, stream>>>(A, S1, S2, LF, Mb);
    gat_write <<<NN, 256, 0, stream>>>(Mb, H, S1, S2, LF, out);
}

// Round 5
// 180.786 us; speedup vs baseline: 1.2443x; 1.2443x over previous
//
#include <hip/hip_runtime.h>
#include <hip/hip_bf16.h>

// Problem constants (reference: N=2048, F=128, HEADS=8, OUT_DIM=8, ALPHA=0.2)
#define NN      2048
#define FDIM    128
#define HEADS   8
#define ODIM    8
#define HID     64      // HEADS*ODIM
#define ALPHA   0.2f
#define NWORDS  (NN / 64)   // 32 u64 mask words per row

__device__ __forceinline__ float lrelu(float x) {
    return x > 0.f ? x : ALPHA * x;
}

// ---------------------------------------------------------------------------
// Kernel 1: h = X @ W  (per-node row), s1 = h . a1, s2 = h . a2  (per head)
// grid = NN blocks, block = 64 threads (1 wave)
// ---------------------------------------------------------------------------
__global__ __launch_bounds__(64) void gat_prep(
        const float* __restrict__ X,   // (NN, FDIM)
        const float* __restrict__ W,   // (FDIM, HID)
        const float* __restrict__ ak,  // (2*ODIM,)
        float* __restrict__ H,         // (NN, HID)
        float* __restrict__ S1,        // (NN, HEADS)
        float* __restrict__ S2) {      // (NN, HEADS)
    const int n = blockIdx.x;
    const int t = threadIdx.x;

    __shared__ float Xs[FDIM];
    __shared__ float hs[HID];

    Xs[t]      = X[(size_t)n * FDIM + t];
    Xs[t + 64] = X[(size_t)n * FDIM + 64 + t];
    __syncthreads();

    float acc = 0.f;
    #pragma unroll 8
    for (int k = 0; k < FDIM; ++k)
        acc = fmaf(Xs[k], W[k * HID + t], acc);   // Xs[k]: LDS broadcast; W col: coalesced

    H[(size_t)n * HID + t] = acc;
    hs[t] = acc;
    __syncthreads();

    if (t < 16) {
        const int head = t & 7;
        const float* a = ak + ((t < 8) ? 0 : ODIM);
        float s = 0.f;
        #pragma unroll
        for (int d = 0; d < ODIM; ++d)
            s = fmaf(hs[head * ODIM + d], a[d], s);
        if (t < 8) S1[n * HEADS + head] = s;
        else       S2[n * HEADS + head] = s;
    }
}

// ---------------------------------------------------------------------------
// Kernel 2: per row i — LF[i,h] = sum_j mask(i,j) * exp(lrelu(s1[i,h]+s2[j,h]))
// Max-free softmax denominator (scores O(1); masked lanes contribute exact 0,
// matching reference exp(-1e9 - m) == 0 in fp32). Also packs the adjacency
// row into a 64-bit-per-64-j ballot bitmask for the write kernel.
// grid = NN blocks, block = 512 (8 waves), 4 j per thread. No LDS staging of A.
// ---------------------------------------------------------------------------
__global__ __launch_bounds__(512) void gat_rowsum(
        const int*   __restrict__ A,    // (NN, NN)
        const float* __restrict__ S1,   // (NN, HEADS)
        const float* __restrict__ S2,   // (NN, HEADS)
        float* __restrict__ LF,         // (NN, HEADS)
        unsigned long long* __restrict__ Mb) {  // (NN, NWORDS)
    const int i    = blockIdx.x;
    const int t    = threadIdx.x;
    const int wave = t >> 6;
    const int lane = t & 63;

    __shared__ float redL[8 * HEADS];

    float s1r[HEADS];
    #pragma unroll
    for (int h = 0; h < HEADS; ++h) s1r[h] = S1[i * HEADS + h];

    float ls[HEADS];
    #pragma unroll
    for (int h = 0; h < HEADS; ++h) ls[h] = 0.f;

    #pragma unroll
    for (int jj = 0; jj < 4; ++jj) {
        const int j = t + jj * 512;
        const bool msk = A[(size_t)i * NN + j] > 0;   // coalesced dword

        // pack mask bits: word index j>>6 = wave + jj*8 (wave-uniform)
        const unsigned long long b = __ballot(msk);
        if (lane == 0) Mb[i * NWORDS + wave + jj * 8] = b;

        const float4 s2a = *(const float4*)(S2 + j * HEADS);
        const float4 s2b = *(const float4*)(S2 + j * HEADS + 4);
        const float s2v[8] = {s2a.x, s2a.y, s2a.z, s2a.w,
                              s2b.x, s2b.y, s2b.z, s2b.w};
        #pragma unroll
        for (int h = 0; h < HEADS; ++h) {
            const float x = s1r[h] + s2v[h];
            ls[h] += msk ? __expf(lrelu(x)) : 0.f;
        }
    }

    #pragma unroll
    for (int h = 0; h < HEADS; ++h) {
        float v = ls[h];
        #pragma unroll
        for (int off = 32; off; off >>= 1)
            v += __shfl_xor(v, off);
        if (lane == 0) redL[wave * HEADS + h] = v;
    }
    __syncthreads();

    if (t < HEADS) {
        float v = 0.f;
        #pragma unroll
        for (int w = 0; w < 8; ++w)
            v += redL[w * HEADS + t];
        LF[i * HEADS + t] = v;
    }
}

// ---------------------------------------------------------------------------
// Kernel 3: pure write stream, ZERO barriers, tiny prologue.
// Per row i: out[i,j,d] = lrelu( sum_h exp(e[i,j,h]) * h[i,h,d] / LF[i,h] ).
// Mask from bitmask (one broadcast 8B load per wave per jj). hh in registers
// via same-address broadcast loads. REGULAR coalesced float4 stores — the
// 128 MiB output fits in the 256 MiB L3, which absorbs the stream at >6.5
// TB/s; nontemporal stores (R4) bypassed it and regressed 46 us.
// grid = NN blocks, block = 256 (4 waves), 8 j per thread
// ---------------------------------------------------------------------------
__global__ __launch_bounds__(256, 4) void gat_write(
        const unsigned long long* __restrict__ Mb,  // (NN, NWORDS)
        const float* __restrict__ H,    // (NN, HID)
        const float* __restrict__ S1,   // (NN, HEADS)
        const float* __restrict__ S2,   // (NN, HEADS)
        const float* __restrict__ LF,   // (NN, HEADS)
        float* __restrict__ out) {      // (NN, NN, ODIM)
    const int i    = blockIdx.x;
    const int t    = threadIdx.x;
    const int wave = t >> 6;
    const int lane = t & 63;

    // --- prologue: all broadcast loads (same address across lanes, L1-hit) ---
    float lfr[HEADS];
    {
        const float4 l0 = *(const float4*)(LF + i * HEADS);
        const float4 l1 = *(const float4*)(LF + i * HEADS + 4);
        lfr[0] = 1.f / l0.x; lfr[1] = 1.f / l0.y;
        lfr[2] = 1.f / l0.z; lfr[3] = 1.f / l0.w;
        lfr[4] = 1.f / l1.x; lfr[5] = 1.f / l1.y;
        lfr[6] = 1.f / l1.z; lfr[7] = 1.f / l1.w;
    }
    float hh[HID];
    #pragma unroll
    for (int k = 0; k < HID; k += 4) {
        const float4 v = *(const float4*)(H + (size_t)i * HID + k);
        const float r = lfr[k >> 3];
        hh[k]     = v.x * r; hh[k + 1] = v.y * r;
        hh[k + 2] = v.z * r; hh[k + 3] = v.w * r;
    }
    float s1r[HEADS];
    #pragma unroll
    for (int h = 0; h < HEADS; ++h) s1r[h] = S1[i * HEADS + h];

    #pragma unroll
    for (int jj = 0; jj < 8; ++jj) {
        const int j = t + jj * 256;
        // word index j>>6 = wave + jj*4: wave-uniform broadcast load
        const unsigned long long m = Mb[i * NWORDS + wave + jj * 4];
        const bool msk = (m >> lane) & 1ull;

        const float4 s2a = *(const float4*)(S2 + j * HEADS);
        const float4 s2b = *(const float4*)(S2 + j * HEADS + 4);
        const float s2v[8] = {s2a.x, s2a.y, s2a.z, s2a.w,
                              s2b.x, s2b.y, s2b.z, s2b.w};

        float p[HEADS];
        #pragma unroll
        for (int h = 0; h < HEADS; ++h) {
            const float x = s1r[h] + s2v[h];
            p[h] = msk ? __expf(lrelu(x)) : 0.f;
        }

        float o[ODIM];
        #pragma unroll
        for (int d = 0; d < ODIM; ++d) o[d] = 0.f;
        #pragma unroll
        for (int h = 0; h < HEADS; ++h) {
            #pragma unroll
            for (int d = 0; d < ODIM; ++d)
                o[d] = fmaf(p[h], hh[h * ODIM + d], o[d]);
        }

        const size_t base = ((size_t)i * NN + j) * ODIM;
        float4 o0, o1;
        o0.x = lrelu(o[0]); o0.y = lrelu(o[1]);
        o0.z = lrelu(o[2]); o0.w = lrelu(o[3]);
        o1.x = lrelu(o[4]); o1.y = lrelu(o[5]);
        o1.z = lrelu(o[6]); o1.w = lrelu(o[7]);
        *(float4*)(out + base)     = o0;   // coalesced 32 B/lane contiguous
        *(float4*)(out + base + 4) = o1;
    }
}

// ---------------------------------------------------------------------------
extern "C" void kernel_launch(void* const* d_in, const int* in_sizes, int n_in,
                              void* d_out, int out_size, void* d_ws, size_t ws_size,
                              hipStream_t stream) {
    const float* X  = (const float*)d_in[0];   // (2048,128) fp32
    const int*   A  = (const int*)  d_in[1];   // (2048,2048) int32
    const float* W  = (const float*)d_in[2];   // (128,64) fp32
    const float* ak = (const float*)d_in[3];   // (16,1) fp32
    float* out = (float*)d_out;                // (2048*2048*8) fp32

    // ws layout: H (512 KB) | S1 (64 KB) | S2 (64 KB) | LF (64 KB) | Mb (512 KB)
    float* H  = (float*)d_ws;
    float* S1 = H  + (size_t)NN * HID;
    float* S2 = S1 + (size_t)NN * HEADS;
    float* LF = S2 + (size_t)NN * HEADS;
    unsigned long long* Mb = (unsigned long long*)(LF + (size_t)NN * HEADS);

    gat_prep  <<<NN,  64, 0, stream>>>(X, W, ak, H, S1, S2);
    gat_rowsum<<<NN, 512, 0, stream>>>(A, S1, S2, LF, Mb);
    gat_write <<<NN, 256, 0, stream>>>(Mb, H, S1, S2, LF, out);
}